// Round 9
// baseline (261.941 us; speedup 1.0000x reference)
//
#include <hip/hip_runtime.h>
#include <limits.h>

// RWKV integer WKV recurrence on MI355X (gfx950) — 4-wave pipeline, round 9.
//
// Round-8 post-mortem (126us, absmax=0, VGPR=84): (1) compiler sank the b128
// ring loads back into the consume loops (64 VGPRs of ev[] can't fit in 84)
// -> per-step LDS latency again; (2) __syncthreads drains vmcnt(0) every
// iteration -> global k/v prefetch never pipelined. Fixes, math untouched:
//   - asm keep-alive after each load batch: forces all ring/LUT loads issued
//     up-front and values pinned in VGPRs (one lgkmcnt wait per iter, not 16).
//   - ring_barrier() = s_waitcnt lgkmcnt(0) + raw s_barrier: LDS ordering only;
//     global loads stay in flight across barriers (counted-vmcnt principle).
//     Parity ring: producer writes p while consumers read 1-p; each wave's own
//     lgkmcnt(0) retires its reads before the swap -> no WAR/RAW hazard.
// Waves: W0 pp/LUT -> ering; W1 aa-chain -> yring[0]; W2 bb-chain -> yring[1];
// W3 f64 divide (exact == div_rne, |aa1|<2^31<<2^52) + store.

#define TPB 256
#define CC  2048
#define TT  1024
#define TB  16
#define NTB (TT / TB)      // 64 blocks + 2 drain iterations

static __device__ __forceinline__ int sat_add(int a, int b) {
#if __has_builtin(__builtin_elementwise_add_sat)
    return __builtin_elementwise_add_sat(a, b);   // v_add_i32 ... clamp
#else
    long long s = (long long)a + (long long)b;
    return s < (long long)INT_MIN ? INT_MIN
         : (s > (long long)INT_MAX ? INT_MAX : (int)s);
#endif
}

// RNE((a*e)/2^14), floor form == reference sign-magnitude RNE (HW-verified
// absmax=0 rounds 5/6/8). Fits int32 for |a| <= 2^31, 0 <= e <= 2^14.
static __device__ __forceinline__ int rne14_s(int a, int e) {
    long long x2 = (long long)a * e + 8192;
    int q1 = (int)((unsigned long long)x2 >> 14);
    int tie = (((unsigned)x2 & 32767u) == 16384u);     // r==8192 && q even
    return q1 - tie;
}

static __device__ __forceinline__ unsigned rne14_u(unsigned a, unsigned e) {
    unsigned long long x2 = (unsigned long long)a * e + 8192u;
    unsigned q1 = (unsigned)(x2 >> 14);
    unsigned tie = (((unsigned)x2 & 32767u) == 16384u);
    return q1 - tie;
}

// Pin a value in a VGPR at this program point (forces preceding load to have
// completed and the value to stay live — defeats load re-sinking).
static __device__ __forceinline__ void keep(int x)      { asm volatile("" :: "v"(x)); }

// LDS-ordered workgroup barrier WITHOUT the vmcnt(0) drain of __syncthreads.
static __device__ __forceinline__ void ring_barrier() {
    asm volatile("s_waitcnt lgkmcnt(0)" ::: "memory");
    __builtin_amdgcn_s_barrier();
}

__launch_bounds__(TPB, 1)
__global__ void wkv_pipe_kernel(const int* __restrict__ w_i, const int* __restrict__ u_i,
                                const int* __restrict__ k_i, const int* __restrict__ v_i,
                                const int* __restrict__ lut, int* __restrict__ y)
{
    __shared__ int slut[1025];
    __shared__ __align__(16) int ering[2][TB][64][4];  // e1,e2,e1n,e2n contiguous/lane
    __shared__ __align__(16) int yring[2][TB][64][2];  // {aa1, dd} contiguous/lane

    for (int i = threadIdx.x; i < 1025; i += TPB) slut[i] = lut[i];
    __syncthreads();                                   // once; full sync is fine here

    const int lane = threadIdx.x & 63;
    const int wid  = threadIdx.x >> 6;
    const int bidx = blockIdx.x;                               // 256 blocks, 1/CU
    const size_t ubase = ((size_t)(bidx >> 5) << 21) + (size_t)((bidx & 31) << 6);

    auto eread = [&](int idx4) -> int {        // lut[clamp(idx4/4,0,1024)] via med3
        idx4 = idx4 < 0 ? 0 : (idx4 > 4096 ? 4096 : idx4);
        return *(const int*)((const char*)slut + idx4);
    };

    if (wid == 0) {
        // -------- W0: pp recurrence + LUT -> ering (reads first, writes after)
        const int ch = ((bidx & 31) << 6) + lane;
        const int w = w_i[ch], u = u_i[ch];
        const int c1  = 4096 - 4 * u;          // byte-index consts: idx=4*delta+4096
        const int c1r = 4096 + 4 * u;
        const int c2  = 4096 + 4 * w;
        const int c2r = 4096 - 4 * w;
        int pp = -32768;
        int kc[TB], kn[TB];
        const int* kb = k_i + ubase;
#pragma unroll
        for (int i = 0; i < TB; ++i) kc[i] = kb[((size_t)i << 11) + lane];
#pragma unroll
        for (int i = 0; i < TB; ++i) kn[i] = kb[((size_t)(TB + i) << 11) + lane];

        for (int j = 0; j < NTB + 2; ++j) {
            if (j < NTB) {
                const int p = j & 1;
                int ea[TB], eb[TB], ec[TB], ed[TB];
                // phase A1: pp chain + issue all 4*TB LUT reads (they don't feed pp)
#pragma unroll
                for (int i = 0; i < TB; ++i) {
                    const int kk = kc[i];
                    const int s = (pp - kk) << 2;              // 4*(pp-kk)
                    ea[i] = eread(s + c1);                     // e1 : 1024+(pp-(k+u))
                    eb[i] = eread(c1r - s);                    // e2 : 1024-(pp-(k+u))
                    ec[i] = eread(s + c2);                     // e1n: 1024+((pp+w)-k)
                    ed[i] = eread(c2r - s);                    // e2n: 1024-((pp+w)-k)
                    const int ppw = pp + w;
                    pp = ppw > kk ? ppw : kk;                  // next pp
                }
#pragma unroll
                for (int i = 0; i < TB; ++i) {                 // pin: loads issued NOW
                    keep(ea[i]); keep(eb[i]); keep(ec[i]); keep(ed[i]);
                }
                // phase A2: vectorized ring writes
#pragma unroll
                for (int i = 0; i < TB; ++i) {
                    int4 t; t.x = ea[i]; t.y = eb[i]; t.z = ec[i]; t.w = ed[i];
                    *(int4*)&ering[p][i][lane][0] = t;         // ds_write_b128
                }
#pragma unroll
                for (int i = 0; i < TB; ++i) kc[i] = kn[i];
                if (j + 2 < NTB) {
                    const int* kbn = k_i + ubase + ((size_t)((j + 2) * TB) << 11);
#pragma unroll
                    for (int i = 0; i < TB; ++i) kn[i] = kbn[((size_t)i << 11) + lane];
                }
            }
            ring_barrier();
        }
    } else if (wid == 1) {
        // -------- W1: aa chain -> yring[.][.][lane][0]
        int aa = 0;
        int vc[TB], vn[TB];
        const int* vb = v_i + ubase;
#pragma unroll
        for (int i = 0; i < TB; ++i) vc[i] = vb[((size_t)i << 11) + lane];
#pragma unroll
        for (int i = 0; i < TB; ++i) vn[i] = vb[((size_t)(TB + i) << 11) + lane];

        for (int j = 0; j < NTB + 2; ++j) {
            const int jb = j - 1;
            if (jb >= 0 && jb < NTB) {
                const int p = jb & 1;
                int4 ev[TB];
#pragma unroll
                for (int i = 0; i < TB; ++i)                   // all b128 loads upfront
                    ev[i] = *(const int4*)&ering[p][i][lane][0];
#pragma unroll
                for (int i = 0; i < TB; ++i) {                 // pin in VGPRs
                    keep(ev[i].x); keep(ev[i].y); keep(ev[i].z); keep(ev[i].w);
                }
#pragma unroll
                for (int i = 0; i < TB; ++i) {
                    const int vv = vc[i];
                    const int aa1 = sat_add(rne14_s(aa, ev[i].x), vv * ev[i].y);
                    yring[p][i][lane][0] = aa1;
                    aa = sat_add(rne14_s(aa1, ev[i].z), vv * ev[i].w);
                }
#pragma unroll
                for (int i = 0; i < TB; ++i) vc[i] = vn[i];
                if (jb + 2 < NTB) {
                    const int* vbn = v_i + ubase + ((size_t)((jb + 2) * TB) << 11);
#pragma unroll
                    for (int i = 0; i < TB; ++i) vn[i] = vbn[((size_t)i << 11) + lane];
                }
            }
            ring_barrier();
        }
    } else if (wid == 2) {
        // -------- W2: bb chain -> yring[.][.][lane][1]
        unsigned bb = 0;
        for (int j = 0; j < NTB + 2; ++j) {
            const int jb = j - 1;
            if (jb >= 0 && jb < NTB) {
                const int p = jb & 1;
                int4 ev[TB];
#pragma unroll
                for (int i = 0; i < TB; ++i)                   // all b128 loads upfront
                    ev[i] = *(const int4*)&ering[p][i][lane][0];
#pragma unroll
                for (int i = 0; i < TB; ++i) {                 // pin in VGPRs
                    keep(ev[i].x); keep(ev[i].y); keep(ev[i].z); keep(ev[i].w);
                }
#pragma unroll
                for (int i = 0; i < TB; ++i) {
                    unsigned bb1 = rne14_u(bb, (unsigned)ev[i].x) + (unsigned)ev[i].y;
                    bb1 = bb1 > 0xFFFFFFu ? 0xFFFFFFu : bb1;   // clip to bb_hi
                    yring[p][i][lane][1] = (int)(bb1 > 1u ? bb1 : 1u); // dd=max(bb1,1)
                    unsigned bb2 = rne14_u(bb1, (unsigned)ev[i].z) + (unsigned)ev[i].w;
                    bb = bb2 > 0xFFFFFFu ? 0xFFFFFFu : bb2;
                }
            }
            ring_barrier();
        }
    } else {
        // -------- W3: y = rint(aa1/dd) in f64 (exact == div_rne) + store
        for (int j = 0; j < NTB + 2; ++j) {
            const int jb = j - 2;
            if (jb >= 0) {                                     // jb <= NTB-1 by bound
                const int p = jb & 1;
                int* yb = y + ubase + ((size_t)(jb * TB) << 11);
                int2 t[TB];
#pragma unroll
                for (int i = 0; i < TB; ++i)                   // all b64 loads upfront
                    t[i] = *(const int2*)&yring[p][i][lane][0];
#pragma unroll
                for (int i = 0; i < TB; ++i) { keep(t[i].x); keep(t[i].y); }
#pragma unroll
                for (int i = 0; i < TB; ++i) {
                    const double qa = (double)t[i].x;          // aa1
                    const double qd = (double)t[i].y;          // dd in [1, 2^24)
                    yb[((size_t)i << 11) + lane] = (int)rint(qa / qd);
                }
            }
            ring_barrier();
        }
    }
}

extern "C" void kernel_launch(void* const* d_in, const int* in_sizes, int n_in,
                              void* d_out, int out_size, void* d_ws, size_t ws_size,
                              hipStream_t stream) {
    const int* w_i = (const int*)d_in[0];
    const int* u_i = (const int*)d_in[1];
    const int* k_i = (const int*)d_in[2];
    const int* v_i = (const int*)d_in[3];
    const int* lut = (const int*)d_in[4];
    int* y = (int*)d_out;
    dim3 grid(8 * CC / 64);                    // 256 blocks x 256 threads (4 waves)
    wkv_pipe_kernel<<<grid, TPB, 0, stream>>>(w_i, u_i, k_i, v_i, lut, y);
}